// Round 3
// baseline (458.863 us; speedup 1.0000x reference)
//
#include <hip/hip_runtime.h>
#include <math.h>

#define DEVI static __device__ __forceinline__

using bf16x8 = __attribute__((ext_vector_type(8))) __bf16;
using f32x4  = __attribute__((ext_vector_type(4))) float;

constexpr int Bb = 2, Tt = 2048, Dd = 2048, NQ = 16, NK = 4, HD = 128;
constexpr int Mrows = Bb * Tt;               // 4096
constexpr int QKC   = NQ*HD + NK*HD;         // 2560 (q,k fp32 cols)
constexpr int VC    = NK*HD;                 // 512
constexpr int KOFF  = NQ*HD;                 // 2048 (row offset of k-weights)
constexpr int VOFF  = NQ*HD + NK*HD;         // 2560 (row offset of v-weights)

DEVI ushort f2b(float f) {                   // fp32 -> bf16 (RNE)
  union { float f; unsigned u; } v; v.f = f;
  unsigned r = v.u + 0x7fffu + ((v.u >> 16) & 1u);
  return (ushort)(r >> 16);
}
DEVI float b2f(ushort u) {
  union { unsigned u; float f; } v; v.u = ((unsigned)u) << 16;
  return v.f;
}
DEVI void split2(float x, ushort& h, ushort& l) {
  ushort hb = f2b(x);
  h = hb;
  l = f2b(x - b2f(hb));
}

typedef const __attribute__((address_space(1))) unsigned* gp1;
typedef __attribute__((address_space(3))) unsigned* lp3;
DEVI void gload16(void* lds, const void* g) {
  __builtin_amdgcn_global_load_lds((gp1)g, (lp3)lds, 16, 0, 0);
}

// ---------------- fp32 -> split bf16 pair ----------------
__global__ void k_split_x(const float* __restrict__ x, ushort* __restrict__ oh,
                          ushort* __restrict__ ol, int n4) {
  int i = blockIdx.x * blockDim.x + threadIdx.x;
  if (i >= n4) return;
  float4 v = ((const float4*)x)[i];
  ushort4 h, l;
  split2(v.x, h.x, l.x); split2(v.y, h.y, l.y);
  split2(v.z, h.z, l.z); split2(v.w, h.w, l.w);
  ((ushort4*)oh)[i] = h;
  ((ushort4*)ol)[i] = l;
}

// ------- transpose + split: in fp32 [R][C] -> hi/lo bf16 [C][R] -------
__global__ void k_tconv_split(const float* __restrict__ in, ushort* __restrict__ outh,
                              ushort* __restrict__ outl, int R, int C) {
  __shared__ float t[32][33];
  const int c0 = blockIdx.x * 32, r0 = blockIdx.y * 32;
  const int tx = threadIdx.x, ty = threadIdx.y;
#pragma unroll
  for (int i = 0; i < 32; i += 8)
    t[ty + i][tx] = in[(size_t)(r0 + ty + i) * C + (c0 + tx)];
  __syncthreads();
#pragma unroll
  for (int i = 0; i < 32; i += 8) {
    ushort h, l;
    split2(t[tx][ty + i], h, l);
    size_t o = (size_t)(c0 + ty + i) * R + (r0 + tx);
    outh[o] = h;
    outl[o] = l;
  }
}

// ------- transpose + convert (single bf16) -------
__global__ void k_tconv(const float* __restrict__ in, ushort* __restrict__ out, int R, int C) {
  __shared__ float t[32][33];
  const int c0 = blockIdx.x * 32, r0 = blockIdx.y * 32;
  const int tx = threadIdx.x, ty = threadIdx.y;
#pragma unroll
  for (int i = 0; i < 32; i += 8)
    t[ty + i][tx] = in[(size_t)(r0 + ty + i) * C + (c0 + tx)];
  __syncthreads();
#pragma unroll
  for (int i = 0; i < 32; i += 8)
    out[(size_t)(c0 + ty + i) * R + (r0 + tx)] = f2b(t[tx][ty + i]);
}

// ---------------- split-precision QKV GEMM ----------------
// A = (Ah+Al) [M][Kd], Bt = (Bh+Bl) [N][Kd]; C = A*Bt^T via AhBh+AhBl+AlBh
// cols < QKC -> fp32 QKf; cols >= QKC -> bf16 Vb (single-term AhBh is enough)
__launch_bounds__(256)
__global__ void k_gemm_qkv(const ushort* __restrict__ Ah, const ushort* __restrict__ Al,
                           const ushort* __restrict__ Bh, const ushort* __restrict__ Bl,
                           float* __restrict__ Cqk, ushort* __restrict__ Cv) {
  __shared__ char Ash[8192], Asl[8192], Bsh[8192], Bsl[8192];
  const int Kd = Dd;
  const int tid = threadIdx.x;
  const int l = tid & 63, w = tid >> 6;
  const int wr = w >> 1, wc = w & 1;
  const int lr = l & 15, lk = l >> 4;
  const size_t row0 = (size_t)blockIdx.y * 128, col0 = (size_t)blockIdx.x * 128;
  const bool vblk = (col0 >= QKC);

  f32x4 acc[4][4];
#pragma unroll
  for (int i = 0; i < 4; ++i)
#pragma unroll
    for (int j = 0; j < 4; ++j) acc[i][j] = (f32x4){0.f, 0.f, 0.f, 0.f};

  const int c0i = tid, c1i = tid + 256;
  const int ra0 = c0i >> 2, sa0 = (c0i & 3) ^ ((ra0 >> 1) & 3);
  const int ra1 = c1i >> 2, sa1 = (c1i & 3) ^ ((ra1 >> 1) & 3);

  for (int kt = 0; kt < Kd; kt += 32) {
    if (kt) __syncthreads();
    size_t a0 = (row0 + ra0) * Kd + kt + sa0 * 8, a1 = (row0 + ra1) * Kd + kt + sa1 * 8;
    size_t b0 = (col0 + ra0) * Kd + kt + sa0 * 8, b1 = (col0 + ra1) * Kd + kt + sa1 * 8;
    gload16(Ash + c0i * 16, Ah + a0);
    gload16(Ash + c1i * 16, Ah + a1);
    gload16(Bsh + c0i * 16, Bh + b0);
    gload16(Bsh + c1i * 16, Bh + b1);
    if (!vblk) {
      gload16(Asl + c0i * 16, Al + a0);
      gload16(Asl + c1i * 16, Al + a1);
      gload16(Bsl + c0i * 16, Bl + b0);
      gload16(Bsl + c1i * 16, Bl + b1);
    }
    __syncthreads();
    bf16x8 fah[4], fal[4], fbh[4], fbl[4];
#pragma unroll
    for (int i = 0; i < 4; ++i) {
      int ra = wr * 64 + i * 16 + lr;
      int ao = ra * 64 + ((lk ^ ((ra >> 1) & 3)) << 4);
      fah[i] = *(const bf16x8*)(Ash + ao);
      int rb = wc * 64 + i * 16 + lr;
      int bo = rb * 64 + ((lk ^ ((rb >> 1) & 3)) << 4);
      fbh[i] = *(const bf16x8*)(Bsh + bo);
      if (!vblk) {
        fal[i] = *(const bf16x8*)(Asl + ao);
        fbl[i] = *(const bf16x8*)(Bsl + bo);
      }
    }
#pragma unroll
    for (int i = 0; i < 4; ++i)
#pragma unroll
      for (int j = 0; j < 4; ++j) {
        acc[i][j] = __builtin_amdgcn_mfma_f32_16x16x32_bf16(fah[i], fbh[j], acc[i][j], 0, 0, 0);
        if (!vblk) {
          acc[i][j] = __builtin_amdgcn_mfma_f32_16x16x32_bf16(fah[i], fbl[j], acc[i][j], 0, 0, 0);
          acc[i][j] = __builtin_amdgcn_mfma_f32_16x16x32_bf16(fal[i], fbh[j], acc[i][j], 0, 0, 0);
        }
      }
  }
  if (!vblk) {
#pragma unroll
    for (int i = 0; i < 4; ++i) {
      size_t r = row0 + wr * 64 + i * 16 + lk * 4;
#pragma unroll
      for (int j = 0; j < 4; ++j) {
        size_t cc = col0 + wc * 64 + j * 16 + lr;
#pragma unroll
        for (int rg = 0; rg < 4; ++rg) Cqk[(r + rg) * QKC + cc] = acc[i][j][rg];
      }
    }
  } else {
#pragma unroll
    for (int i = 0; i < 4; ++i) {
      size_t r = row0 + wr * 64 + i * 16 + lk * 4;
#pragma unroll
      for (int j = 0; j < 4; ++j) {
        size_t cc = col0 + wc * 64 + j * 16 + lr - QKC;
#pragma unroll
        for (int rg = 0; rg < 4; ++rg) Cv[(r + rg) * VC + cc] = f2b(acc[i][j][rg]);
      }
    }
  }
}

// ---------------- plain bf16 GEMM (out-proj) ----------------
__launch_bounds__(256)
__global__ void k_gemm_bt(const ushort* __restrict__ A, const ushort* __restrict__ Bt,
                          float* __restrict__ C, int M, int N, int Kd) {
  __shared__ char As[8192];
  __shared__ char Bs[8192];
  const int tid = threadIdx.x;
  const int l = tid & 63, w = tid >> 6;
  const int wr = w >> 1, wc = w & 1;
  const int lr = l & 15, lk = l >> 4;
  const size_t row0 = (size_t)blockIdx.y * 128, col0 = (size_t)blockIdx.x * 128;

  f32x4 acc[4][4];
#pragma unroll
  for (int i = 0; i < 4; ++i)
#pragma unroll
    for (int j = 0; j < 4; ++j) acc[i][j] = (f32x4){0.f, 0.f, 0.f, 0.f};

  const int c0i = tid, c1i = tid + 256;
  const int ra0 = c0i >> 2, sa0 = (c0i & 3) ^ ((ra0 >> 1) & 3);
  const int ra1 = c1i >> 2, sa1 = (c1i & 3) ^ ((ra1 >> 1) & 3);

  for (int kt = 0; kt < Kd; kt += 32) {
    if (kt) __syncthreads();
    gload16(As + c0i * 16, A + (row0 + ra0) * Kd + kt + sa0 * 8);
    gload16(As + c1i * 16, A + (row0 + ra1) * Kd + kt + sa1 * 8);
    gload16(Bs + c0i * 16, Bt + (col0 + ra0) * Kd + kt + sa0 * 8);
    gload16(Bs + c1i * 16, Bt + (col0 + ra1) * Kd + kt + sa1 * 8);
    __syncthreads();
    bf16x8 af[4], bfr[4];
#pragma unroll
    for (int i = 0; i < 4; ++i) {
      int ra = wr * 64 + i * 16 + lr;
      af[i] = *(const bf16x8*)(As + ra * 64 + ((lk ^ ((ra >> 1) & 3)) << 4));
      int rb = wc * 64 + i * 16 + lr;
      bfr[i] = *(const bf16x8*)(Bs + rb * 64 + ((lk ^ ((rb >> 1) & 3)) << 4));
    }
#pragma unroll
    for (int i = 0; i < 4; ++i)
#pragma unroll
      for (int j = 0; j < 4; ++j)
        acc[i][j] = __builtin_amdgcn_mfma_f32_16x16x32_bf16(af[i], bfr[j], acc[i][j], 0, 0, 0);
  }
#pragma unroll
  for (int i = 0; i < 4; ++i) {
    size_t r = row0 + wr * 64 + i * 16 + lk * 4;
#pragma unroll
    for (int j = 0; j < 4; ++j) {
      size_t cc = col0 + wc * 64 + j * 16 + lr;
#pragma unroll
      for (int rg = 0; rg < 4; ++rg) C[(r + rg) * N + cc] = acc[i][j][rg];
    }
  }
}

// ---------------- RoPE table (double-precision trig) ----------------
__global__ void k_rope_tab(const int* __restrict__ pos, float* __restrict__ tab) {
  int idx = blockIdx.x * blockDim.x + threadIdx.x;
  if (idx >= Mrows * 64) return;
  int m = idx >> 6, i = idx & 63;
  double a = (double)pos[m] * exp2(-0.20762050593045952 * (double)i);
  tab[idx * 2]     = (float)cos(a);
  tab[idx * 2 + 1] = (float)sin(a);
}

// ------- RoPE: fp32 QKf -> rotated, split to hi/lo bf16 (Q and K) -------
__global__ void k_rope(const float* __restrict__ qkf, const float* __restrict__ tab,
                       ushort* __restrict__ Qh, ushort* __restrict__ Ql,
                       ushort* __restrict__ Kh, ushort* __restrict__ Kl) {
  int idx = blockIdx.x * blockDim.x + threadIdx.x;
  if (idx >= Mrows * 20 * 8) return;
  int chunk = idx & 7;
  int h20 = (idx >> 3) % 20;    // 16 q heads then 4 k heads
  int m = idx / 160;
  const float* p = qkf + (size_t)m * QKC + h20 * 128 + chunk * 8;
  float4 x1a = *(const float4*)p,        x1b = *(const float4*)(p + 4);
  float4 x2a = *(const float4*)(p + 64), x2b = *(const float4*)(p + 68);
  float x1[8] = {x1a.x, x1a.y, x1a.z, x1a.w, x1b.x, x1b.y, x1b.z, x1b.w};
  float x2[8] = {x2a.x, x2a.y, x2a.z, x2a.w, x2b.x, x2b.y, x2b.z, x2b.w};
  const float* tp = tab + ((size_t)m * 64 + chunk * 8) * 2;
  ushort4 h1[2], l1[2], h2[2], l2[2];
#pragma unroll
  for (int j = 0; j < 8; ++j) {
    float c = tp[2 * j], s = tp[2 * j + 1];
    float o1 = x1[j] * c - x2[j] * s;
    float o2 = x2[j] * c + x1[j] * s;
    ushort hh, ll;
    split2(o1, hh, ll);
    ((ushort*)h1)[j] = hh; ((ushort*)l1)[j] = ll;
    split2(o2, hh, ll);
    ((ushort*)h2)[j] = hh; ((ushort*)l2)[j] = ll;
  }
  size_t base;
  ushort *oh, *ol;
  if (h20 < 16) { base = (size_t)m * 2048 + h20 * 128 + chunk * 8; oh = Qh; ol = Ql; }
  else          { base = (size_t)m * 512 + (h20 - 16) * 128 + chunk * 8; oh = Kh; ol = Kl; }
  *(ushort4*)(oh + base)      = h1[0];
  *(ushort4*)(oh + base + 4)  = h1[1];
  *(ushort4*)(ol + base)      = l1[0];
  *(ushort4*)(ol + base + 4)  = l1[1];
  *(ushort4*)(oh + base + 64) = h2[0];
  *(ushort4*)(oh + base + 68) = h2[1];
  *(ushort4*)(ol + base + 64) = l2[0];
  *(ushort4*)(ol + base + 68) = l2[1];
}

// ------- V transpose: Vb [M][VC] -> VT[(b*4+g)*128 + h][s] -------
__global__ void k_vt(const ushort* __restrict__ vb, ushort* __restrict__ vt) {
  __shared__ ushort t[32][33];
  const int bg = blockIdx.z, bq = bg >> 2, g = bg & 3;
  const int s0 = blockIdx.x * 32, h0 = blockIdx.y * 32;
  const int tx = threadIdx.x, ty = threadIdx.y;
#pragma unroll
  for (int i = 0; i < 32; i += 8)
    t[ty + i][tx] = vb[(size_t)(bq * Tt + s0 + ty + i) * VC + g * HD + h0 + tx];
  __syncthreads();
#pragma unroll
  for (int i = 0; i < 32; i += 8)
    vt[((size_t)bg * HD + h0 + ty + i) * Tt + (s0 + tx)] = t[tx][ty + i];
}

// ---------------- causal GQA flash attention v2 ----------------
// 512 threads / 8 waves; QB=128 q-rows per block (wave w: 16 rows at t0+w*16);
// KVBLK=64. K-hi + V^T staged in LDS (XOR swizzle); K-lo frags direct from L2.
// 1-D grid of 512 blocks; qt paired (15-p, p) so co-resident blocks sum to
// constant work.
__launch_bounds__(512, 4)
__global__ void k_flash(const ushort* __restrict__ Qhg, const ushort* __restrict__ Qlg,
                        const ushort* __restrict__ Khg, const ushort* __restrict__ Klg,
                        const ushort* __restrict__ vt, ushort* __restrict__ attn) {
  __shared__ char Ksh[64 * 256];   // K hi [s][h] bf16, XOR swizzle ((s&7)<<4)
  __shared__ char Vs[128 * 128];   // V^T [h][s] bf16, XOR swizzle ((h&7)<<4)
  __shared__ char Pl[8][2176];     // per-wave P: 16 rows x 136B pitch
  const int b = blockIdx.x;
  const int vv = b >> 8, u = b & 255;
  const int hid = u >> 3, p = u & 7;
  const int qt = vv ? p : (15 - p);           // paired workload balance
  const int bq = hid >> 4, n = hid & 15, g = n >> 2;
  const int tid = threadIdx.x, w = tid >> 6, l = tid & 63;
  const int lr = l & 15, lk = l >> 4;
  const int t0 = qt * 128;
  const int qrow = t0 + w * 16;

  bf16x8 qfh[4], qfl[4];
  {
    const size_t qb = ((size_t)(bq * Tt + qrow + lr)) * 2048 + n * HD + lk * 8;
#pragma unroll
    for (int kt = 0; kt < 4; ++kt) {
      qfh[kt] = *(const bf16x8*)(Qhg + qb + kt * 32);
      qfl[kt] = *(const bf16x8*)(Qlg + qb + kt * 32);
    }
  }
  f32x4 O[8];
#pragma unroll
  for (int hb = 0; hb < 8; ++hb) O[hb] = (f32x4){0.f, 0.f, 0.f, 0.f};
  float mrow[4] = {-INFINITY, -INFINITY, -INFINITY, -INFINITY};
  float lrow[4] = {0.f, 0.f, 0.f, 0.f};

  const size_t kgbase = (size_t)(bq * Tt) * VC + g * HD;
  const size_t vgbase = (size_t)(bq * 4 + g) * HD * Tt;
  const int ntiles = 2 * qt + 2;

  for (int j = 0; j < ntiles; ++j) {
    const int s0 = j * 64;
    if (j) __syncthreads();
    // stage K-hi (64x128 bf16 = 1024 chunks) and V^T (128x64 = 1024 chunks)
#pragma unroll
    for (int cc = 0; cc < 2; ++cc) {
      int c = cc * 512 + tid;
      int srow = c >> 4;
      int oin = ((c & 15) << 4) ^ ((srow & 7) << 4);
      gload16(Ksh + c * 16, Khg + kgbase + (size_t)(s0 + srow) * VC + (oin >> 1));
      int hrow = c >> 3;
      int oinV = ((c & 7) << 4) ^ ((hrow & 7) << 4);
      gload16(Vs + c * 16, vt + vgbase + (size_t)hrow * Tt + s0 + (oinV >> 1));
    }
    __syncthreads();
    if (s0 > qrow + 15) continue;   // tile fully masked for this wave
    f32x4 sc[4];
#pragma unroll
    for (int ns = 0; ns < 4; ++ns) {
      f32x4 a = (f32x4){0.f, 0.f, 0.f, 0.f};
      int sl = ns * 16 + lr;
      const ushort* klp = Klg + kgbase + (size_t)(s0 + sl) * VC + lk * 8;
#pragma unroll
      for (int kt = 0; kt < 4; ++kt) {
        int inner = (kt * 64 + lk * 16) ^ ((sl & 7) << 4);
        bf16x8 kfh = *(const bf16x8*)(Ksh + sl * 256 + inner);
        bf16x8 kfl = *(const bf16x8*)(klp + kt * 32);
        a = __builtin_amdgcn_mfma_f32_16x16x32_bf16(qfh[kt], kfh, a, 0, 0, 0);
        a = __builtin_amdgcn_mfma_f32_16x16x32_bf16(qfl[kt], kfh, a, 0, 0, 0);
        a = __builtin_amdgcn_mfma_f32_16x16x32_bf16(qfh[kt], kfl, a, 0, 0, 0);
      }
      sc[ns] = a;
    }
    if (s0 + 63 > qrow) {           // diagonal tile for this wave: mask s > t
#pragma unroll
      for (int ns = 0; ns < 4; ++ns) {
        int scol = s0 + ns * 16 + lr;
#pragma unroll
        for (int r = 0; r < 4; ++r)
          if (scol > qrow + lk * 4 + r) sc[ns][r] = -INFINITY;
      }
    }
    float scl[4], rs[4];
#pragma unroll
    for (int r = 0; r < 4; ++r) {
      float v0 = fmaxf(fmaxf(sc[0][r], sc[1][r]), fmaxf(sc[2][r], sc[3][r]));
#pragma unroll
      for (int d = 1; d < 16; d <<= 1) v0 = fmaxf(v0, __shfl_xor(v0, d));
      float mn = fmaxf(mrow[r], v0);
      scl[r] = __expf(mrow[r] - mn);
      mrow[r] = mn;
      rs[r] = 0.f;
    }
#pragma unroll
    for (int ns = 0; ns < 4; ++ns)
#pragma unroll
      for (int r = 0; r < 4; ++r) {
        float pv = __expf(sc[ns][r] - mrow[r]);
        rs[r] += pv;
        *(ushort*)(Pl[w] + (lk * 4 + r) * 136 + (ns * 16 + lr) * 2) = f2b(pv);
      }
#pragma unroll
    for (int r = 0; r < 4; ++r) {
#pragma unroll
      for (int d = 1; d < 16; d <<= 1) rs[r] += __shfl_xor(rs[r], d);
      lrow[r] = lrow[r] * scl[r] + rs[r];
    }
#pragma unroll
    for (int hb = 0; hb < 8; ++hb)
#pragma unroll
      for (int r = 0; r < 4; ++r) O[hb][r] *= scl[r];
    // PV: P[16][64] x V[64][128]; A-frag from Pl via 2x b64 (pitch 136)
    union U8 { uint2 u[2]; bf16x8 v; };
    U8 pa0, pa1;
    const char* pb = Pl[w] + lr * 136 + lk * 16;
    pa0.u[0] = *(const uint2*)(pb);
    pa0.u[1] = *(const uint2*)(pb + 8);
    pa1.u[0] = *(const uint2*)(pb + 64);
    pa1.u[1] = *(const uint2*)(pb + 72);
#pragma unroll
    for (int hb = 0; hb < 8; ++hb) {
      int h = hb * 16 + lr;
      int inner0 = (lk * 16) ^ ((h & 7) << 4);
      bf16x8 vf0 = *(const bf16x8*)(Vs + h * 128 + inner0);
      O[hb] = __builtin_amdgcn_mfma_f32_16x16x32_bf16(pa0.v, vf0, O[hb], 0, 0, 0);
      int inner1 = (64 + lk * 16) ^ ((h & 7) << 4);
      bf16x8 vf1 = *(const bf16x8*)(Vs + h * 128 + inner1);
      O[hb] = __builtin_amdgcn_mfma_f32_16x16x32_bf16(pa1.v, vf1, O[hb], 0, 0, 0);
    }
  }
  float inv[4];
#pragma unroll
  for (int r = 0; r < 4; ++r) inv[r] = 1.f / lrow[r];
#pragma unroll
  for (int hb = 0; hb < 8; ++hb)
#pragma unroll
    for (int r = 0; r < 4; ++r) {
      size_t orow = (size_t)(bq * Tt + qrow + lk * 4 + r);
      attn[orow * 2048 + n * HD + hb * 16 + lr] = f2b(O[hb][r] * inv[r]);
    }
}

// ---------------- launch ----------------
extern "C" void kernel_launch(void* const* d_in, const int* in_sizes, int n_in,
                              void* d_out, int out_size, void* d_ws, size_t ws_size,
                              hipStream_t stream) {
  const float* X  = (const float*)d_in[0];
  const int*   qp = (const int*)d_in[1];
  const float* Wq = (const float*)d_in[2];
  const float* Wk = (const float*)d_in[3];
  const float* Wv = (const float*)d_in[4];
  const float* Wo = (const float*)d_in[5];
  float* out = (float*)d_out;
  char* ws = (char*)d_ws;

  ushort* Xh     = (ushort*)(ws + 0);            // 16.78 MB  (-> Qh after GEMM)
  ushort* Xl     = (ushort*)(ws + 16777216);     // 16.78 MB  (-> Ql)
  ushort* WqkvTh = (ushort*)(ws + 33554432);     // 12.58 MB  (-> Kh,Kl,VT)
  ushort* WqkvTl = (ushort*)(ws + 46137344);     // 12.58 MB
  ushort* WoT    = (ushort*)(ws + 58720256);     //  8.39 MB
  float*  QKf    = (float*) (ws + 67108864);     // 41.94 MB  (-> attn)
  ushort* Vb     = (ushort*)(ws + 109051904);    //  4.19 MB
  float*  tab    = (float*) (ws + 113246208);    //  2.10 MB  (end ~115.3 MB)

  ushort* Qh   = Xh;
  ushort* Ql   = Xl;
  ushort* Kh   = (ushort*)(ws + 33554432);
  ushort* Kl   = (ushort*)(ws + 37748736);
  ushort* VT   = (ushort*)(ws + 41943040);
  ushort* attn = (ushort*)(ws + 67108864);

  dim3 tb(32, 8);
  k_split_x<<<(Mrows * Dd / 4 + 255) / 256, 256, 0, stream>>>(X, Xh, Xl, Mrows * Dd / 4);
  k_tconv_split<<<dim3(64, 64), tb, 0, stream>>>(Wq, WqkvTh, WqkvTl, Dd, 2048);
  k_tconv_split<<<dim3(16, 64), tb, 0, stream>>>(Wk, WqkvTh + (size_t)KOFF * Dd,
                                                 WqkvTl + (size_t)KOFF * Dd, Dd, 512);
  k_tconv_split<<<dim3(16, 64), tb, 0, stream>>>(Wv, WqkvTh + (size_t)VOFF * Dd,
                                                 WqkvTl + (size_t)VOFF * Dd, Dd, 512);
  k_tconv<<<dim3(64, 64), tb, 0, stream>>>(Wo, WoT, 2048, 2048);
  k_gemm_qkv<<<dim3(24, 32), 256, 0, stream>>>(Xh, Xl, WqkvTh, WqkvTl, QKf, Vb);
  k_rope_tab<<<(Mrows * 64 + 255) / 256, 256, 0, stream>>>(qp, tab);
  k_rope<<<(Mrows * 160 + 255) / 256, 256, 0, stream>>>(QKf, tab, Qh, Ql, Kh, Kl);
  k_vt<<<dim3(Tt / 32, HD / 32, Bb * NK), tb, 0, stream>>>(Vb, VT);
  k_flash<<<dim3(512), 512, 0, stream>>>(Qh, Ql, Kh, Kl, VT, attn);
  k_gemm_bt<<<dim3(Dd / 128, Mrows / 128), 256, 0, stream>>>(attn, WoT, out, Mrows, Dd, Dd);
}

// Round 4
// 359.104 us; speedup vs baseline: 1.2778x; 1.2778x over previous
//
#include <hip/hip_runtime.h>
#include <math.h>

#define DEVI static __device__ __forceinline__

using bf16x8 = __attribute__((ext_vector_type(8))) __bf16;
using f32x4  = __attribute__((ext_vector_type(4))) float;

constexpr int Bb = 2, Tt = 2048, Dd = 2048, NQ = 16, NK = 4, HD = 128;
constexpr int Mrows = Bb * Tt;               // 4096
constexpr int QKC   = NQ*HD + NK*HD;         // 2560 (q,k fp32 cols)
constexpr int VC    = NK*HD;                 // 512
constexpr int KOFF  = NQ*HD;                 // 2048 (row offset of k-weights)
constexpr int VOFF  = NQ*HD + NK*HD;         // 2560 (row offset of v-weights)

DEVI ushort f2b(float f) {                   // fp32 -> bf16 (RNE)
  union { float f; unsigned u; } v; v.f = f;
  unsigned r = v.u + 0x7fffu + ((v.u >> 16) & 1u);
  return (ushort)(r >> 16);
}
DEVI float b2f(ushort u) {
  union { unsigned u; float f; } v; v.u = ((unsigned)u) << 16;
  return v.f;
}
DEVI void split2(float x, ushort& h, ushort& l) {
  ushort hb = f2b(x);
  h = hb;
  l = f2b(x - b2f(hb));
}

typedef const __attribute__((address_space(1))) unsigned* gp1;
typedef __attribute__((address_space(3))) unsigned* lp3;
DEVI void gload16(void* lds, const void* g) {
  __builtin_amdgcn_global_load_lds((gp1)g, (lp3)lds, 16, 0, 0);
}

// ---------------- fp32 -> split bf16 pair ----------------
__global__ void k_split_x(const float* __restrict__ x, ushort* __restrict__ oh,
                          ushort* __restrict__ ol, int n4) {
  int i = blockIdx.x * blockDim.x + threadIdx.x;
  if (i >= n4) return;
  float4 v = ((const float4*)x)[i];
  ushort4 h, l;
  split2(v.x, h.x, l.x); split2(v.y, h.y, l.y);
  split2(v.z, h.z, l.z); split2(v.w, h.w, l.w);
  ((ushort4*)oh)[i] = h;
  ((ushort4*)ol)[i] = l;
}

// ------- transpose + split: in fp32 [R][C] -> hi/lo bf16 [C][R] -------
__global__ void k_tconv_split(const float* __restrict__ in, ushort* __restrict__ outh,
                              ushort* __restrict__ outl, int R, int C) {
  __shared__ float t[32][33];
  const int c0 = blockIdx.x * 32, r0 = blockIdx.y * 32;
  const int tx = threadIdx.x, ty = threadIdx.y;
#pragma unroll
  for (int i = 0; i < 32; i += 8)
    t[ty + i][tx] = in[(size_t)(r0 + ty + i) * C + (c0 + tx)];
  __syncthreads();
#pragma unroll
  for (int i = 0; i < 32; i += 8) {
    ushort h, l;
    split2(t[tx][ty + i], h, l);
    size_t o = (size_t)(c0 + ty + i) * R + (r0 + tx);
    outh[o] = h;
    outl[o] = l;
  }
}

// ------- transpose + convert (single bf16) -------
__global__ void k_tconv(const float* __restrict__ in, ushort* __restrict__ out, int R, int C) {
  __shared__ float t[32][33];
  const int c0 = blockIdx.x * 32, r0 = blockIdx.y * 32;
  const int tx = threadIdx.x, ty = threadIdx.y;
#pragma unroll
  for (int i = 0; i < 32; i += 8)
    t[ty + i][tx] = in[(size_t)(r0 + ty + i) * C + (c0 + tx)];
  __syncthreads();
#pragma unroll
  for (int i = 0; i < 32; i += 8)
    out[(size_t)(c0 + ty + i) * R + (r0 + tx)] = f2b(t[tx][ty + i]);
}

// ---------------- split-precision QKV GEMM ----------------
// A = (Ah+Al) [M][Kd], Bt = (Bh+Bl) [N][Kd]; C = A*Bt^T via AhBh+AhBl+AlBh
// cols < QKC -> fp32 QKf; cols >= QKC -> bf16 Vb (single-term AhBh is enough)
__launch_bounds__(256)
__global__ void k_gemm_qkv(const ushort* __restrict__ Ah, const ushort* __restrict__ Al,
                           const ushort* __restrict__ Bh, const ushort* __restrict__ Bl,
                           float* __restrict__ Cqk, ushort* __restrict__ Cv) {
  __shared__ char Ash[8192], Asl[8192], Bsh[8192], Bsl[8192];
  const int Kd = Dd;
  const int tid = threadIdx.x;
  const int l = tid & 63, w = tid >> 6;
  const int wr = w >> 1, wc = w & 1;
  const int lr = l & 15, lk = l >> 4;
  const size_t row0 = (size_t)blockIdx.y * 128, col0 = (size_t)blockIdx.x * 128;
  const bool vblk = (col0 >= QKC);

  f32x4 acc[4][4];
#pragma unroll
  for (int i = 0; i < 4; ++i)
#pragma unroll
    for (int j = 0; j < 4; ++j) acc[i][j] = (f32x4){0.f, 0.f, 0.f, 0.f};

  const int c0i = tid, c1i = tid + 256;
  const int ra0 = c0i >> 2, sa0 = (c0i & 3) ^ ((ra0 >> 1) & 3);
  const int ra1 = c1i >> 2, sa1 = (c1i & 3) ^ ((ra1 >> 1) & 3);

  for (int kt = 0; kt < Kd; kt += 32) {
    if (kt) __syncthreads();
    size_t a0 = (row0 + ra0) * Kd + kt + sa0 * 8, a1 = (row0 + ra1) * Kd + kt + sa1 * 8;
    size_t b0 = (col0 + ra0) * Kd + kt + sa0 * 8, b1 = (col0 + ra1) * Kd + kt + sa1 * 8;
    gload16(Ash + c0i * 16, Ah + a0);
    gload16(Ash + c1i * 16, Ah + a1);
    gload16(Bsh + c0i * 16, Bh + b0);
    gload16(Bsh + c1i * 16, Bh + b1);
    if (!vblk) {
      gload16(Asl + c0i * 16, Al + a0);
      gload16(Asl + c1i * 16, Al + a1);
      gload16(Bsl + c0i * 16, Bl + b0);
      gload16(Bsl + c1i * 16, Bl + b1);
    }
    __syncthreads();
    bf16x8 fah[4], fal[4], fbh[4], fbl[4];
#pragma unroll
    for (int i = 0; i < 4; ++i) {
      int ra = wr * 64 + i * 16 + lr;
      int ao = ra * 64 + ((lk ^ ((ra >> 1) & 3)) << 4);
      fah[i] = *(const bf16x8*)(Ash + ao);
      int rb = wc * 64 + i * 16 + lr;
      int bo = rb * 64 + ((lk ^ ((rb >> 1) & 3)) << 4);
      fbh[i] = *(const bf16x8*)(Bsh + bo);
      if (!vblk) {
        fal[i] = *(const bf16x8*)(Asl + ao);
        fbl[i] = *(const bf16x8*)(Bsl + bo);
      }
    }
#pragma unroll
    for (int i = 0; i < 4; ++i)
#pragma unroll
      for (int j = 0; j < 4; ++j) {
        acc[i][j] = __builtin_amdgcn_mfma_f32_16x16x32_bf16(fah[i], fbh[j], acc[i][j], 0, 0, 0);
        if (!vblk) {
          acc[i][j] = __builtin_amdgcn_mfma_f32_16x16x32_bf16(fah[i], fbl[j], acc[i][j], 0, 0, 0);
          acc[i][j] = __builtin_amdgcn_mfma_f32_16x16x32_bf16(fal[i], fbh[j], acc[i][j], 0, 0, 0);
        }
      }
  }
  if (!vblk) {
#pragma unroll
    for (int i = 0; i < 4; ++i) {
      size_t r = row0 + wr * 64 + i * 16 + lk * 4;
#pragma unroll
      for (int j = 0; j < 4; ++j) {
        size_t cc = col0 + wc * 64 + j * 16 + lr;
#pragma unroll
        for (int rg = 0; rg < 4; ++rg) Cqk[(r + rg) * QKC + cc] = acc[i][j][rg];
      }
    }
  } else {
#pragma unroll
    for (int i = 0; i < 4; ++i) {
      size_t r = row0 + wr * 64 + i * 16 + lk * 4;
#pragma unroll
      for (int j = 0; j < 4; ++j) {
        size_t cc = col0 + wc * 64 + j * 16 + lr - QKC;
#pragma unroll
        for (int rg = 0; rg < 4; ++rg) Cv[(r + rg) * VC + cc] = f2b(acc[i][j][rg]);
      }
    }
  }
}

// ---------------- plain bf16 GEMM (out-proj) ----------------
__launch_bounds__(256)
__global__ void k_gemm_bt(const ushort* __restrict__ A, const ushort* __restrict__ Bt,
                          float* __restrict__ C, int M, int N, int Kd) {
  __shared__ char As[8192];
  __shared__ char Bs[8192];
  const int tid = threadIdx.x;
  const int l = tid & 63, w = tid >> 6;
  const int wr = w >> 1, wc = w & 1;
  const int lr = l & 15, lk = l >> 4;
  const size_t row0 = (size_t)blockIdx.y * 128, col0 = (size_t)blockIdx.x * 128;

  f32x4 acc[4][4];
#pragma unroll
  for (int i = 0; i < 4; ++i)
#pragma unroll
    for (int j = 0; j < 4; ++j) acc[i][j] = (f32x4){0.f, 0.f, 0.f, 0.f};

  const int c0i = tid, c1i = tid + 256;
  const int ra0 = c0i >> 2, sa0 = (c0i & 3) ^ ((ra0 >> 1) & 3);
  const int ra1 = c1i >> 2, sa1 = (c1i & 3) ^ ((ra1 >> 1) & 3);

  for (int kt = 0; kt < Kd; kt += 32) {
    if (kt) __syncthreads();
    gload16(As + c0i * 16, A + (row0 + ra0) * Kd + kt + sa0 * 8);
    gload16(As + c1i * 16, A + (row0 + ra1) * Kd + kt + sa1 * 8);
    gload16(Bs + c0i * 16, Bt + (col0 + ra0) * Kd + kt + sa0 * 8);
    gload16(Bs + c1i * 16, Bt + (col0 + ra1) * Kd + kt + sa1 * 8);
    __syncthreads();
    bf16x8 af[4], bfr[4];
#pragma unroll
    for (int i = 0; i < 4; ++i) {
      int ra = wr * 64 + i * 16 + lr;
      af[i] = *(const bf16x8*)(As + ra * 64 + ((lk ^ ((ra >> 1) & 3)) << 4));
      int rb = wc * 64 + i * 16 + lr;
      bfr[i] = *(const bf16x8*)(Bs + rb * 64 + ((lk ^ ((rb >> 1) & 3)) << 4));
    }
#pragma unroll
    for (int i = 0; i < 4; ++i)
#pragma unroll
      for (int j = 0; j < 4; ++j)
        acc[i][j] = __builtin_amdgcn_mfma_f32_16x16x32_bf16(af[i], bfr[j], acc[i][j], 0, 0, 0);
  }
#pragma unroll
  for (int i = 0; i < 4; ++i) {
    size_t r = row0 + wr * 64 + i * 16 + lk * 4;
#pragma unroll
    for (int j = 0; j < 4; ++j) {
      size_t cc = col0 + wc * 64 + j * 16 + lr;
#pragma unroll
      for (int rg = 0; rg < 4; ++rg) C[(r + rg) * N + cc] = acc[i][j][rg];
    }
  }
}

// ---------------- RoPE table (double-precision trig) ----------------
__global__ void k_rope_tab(const int* __restrict__ pos, float* __restrict__ tab) {
  int idx = blockIdx.x * blockDim.x + threadIdx.x;
  if (idx >= Mrows * 64) return;
  int m = idx >> 6, i = idx & 63;
  double a = (double)pos[m] * exp2(-0.20762050593045952 * (double)i);
  tab[idx * 2]     = (float)cos(a);
  tab[idx * 2 + 1] = (float)sin(a);
}

// ------- RoPE: fp32 QKf -> rotated, split to hi/lo bf16 (Q and K) -------
__global__ void k_rope(const float* __restrict__ qkf, const float* __restrict__ tab,
                       ushort* __restrict__ Qh, ushort* __restrict__ Ql,
                       ushort* __restrict__ Kh, ushort* __restrict__ Kl) {
  int idx = blockIdx.x * blockDim.x + threadIdx.x;
  if (idx >= Mrows * 20 * 8) return;
  int chunk = idx & 7;
  int h20 = (idx >> 3) % 20;    // 16 q heads then 4 k heads
  int m = idx / 160;
  const float* p = qkf + (size_t)m * QKC + h20 * 128 + chunk * 8;
  float4 x1a = *(const float4*)p,        x1b = *(const float4*)(p + 4);
  float4 x2a = *(const float4*)(p + 64), x2b = *(const float4*)(p + 68);
  float x1[8] = {x1a.x, x1a.y, x1a.z, x1a.w, x1b.x, x1b.y, x1b.z, x1b.w};
  float x2[8] = {x2a.x, x2a.y, x2a.z, x2a.w, x2b.x, x2b.y, x2b.z, x2b.w};
  const float* tp = tab + ((size_t)m * 64 + chunk * 8) * 2;
  ushort4 h1[2], l1[2], h2[2], l2[2];
#pragma unroll
  for (int j = 0; j < 8; ++j) {
    float c = tp[2 * j], s = tp[2 * j + 1];
    float o1 = x1[j] * c - x2[j] * s;
    float o2 = x2[j] * c + x1[j] * s;
    ushort hh, ll;
    split2(o1, hh, ll);
    ((ushort*)h1)[j] = hh; ((ushort*)l1)[j] = ll;
    split2(o2, hh, ll);
    ((ushort*)h2)[j] = hh; ((ushort*)l2)[j] = ll;
  }
  size_t base;
  ushort *oh, *ol;
  if (h20 < 16) { base = (size_t)m * 2048 + h20 * 128 + chunk * 8; oh = Qh; ol = Ql; }
  else          { base = (size_t)m * 512 + (h20 - 16) * 128 + chunk * 8; oh = Kh; ol = Kl; }
  *(ushort4*)(oh + base)      = h1[0];
  *(ushort4*)(oh + base + 4)  = h1[1];
  *(ushort4*)(ol + base)      = l1[0];
  *(ushort4*)(ol + base + 4)  = l1[1];
  *(ushort4*)(oh + base + 64) = h2[0];
  *(ushort4*)(oh + base + 68) = h2[1];
  *(ushort4*)(ol + base + 64) = l2[0];
  *(ushort4*)(ol + base + 68) = l2[1];
}

// ------- V transpose: Vb [M][VC] -> VT[(b*4+g)*128 + h][s] -------
__global__ void k_vt(const ushort* __restrict__ vb, ushort* __restrict__ vt) {
  __shared__ ushort t[32][33];
  const int bg = blockIdx.z, bq = bg >> 2, g = bg & 3;
  const int s0 = blockIdx.x * 32, h0 = blockIdx.y * 32;
  const int tx = threadIdx.x, ty = threadIdx.y;
#pragma unroll
  for (int i = 0; i < 32; i += 8)
    t[ty + i][tx] = vb[(size_t)(bq * Tt + s0 + ty + i) * VC + g * HD + h0 + tx];
  __syncthreads();
#pragma unroll
  for (int i = 0; i < 32; i += 8)
    vt[((size_t)bg * HD + h0 + ty + i) * Tt + (s0 + tx)] = t[tx][ty + i];
}

// ---------------- causal GQA flash attention v3: 2-phase double-buffer ----------------
// 512 threads / 8 waves; QB=128 q-rows per block (wave w: 16 rows at t0+w*16);
// KVBLK=64. K-hi, K-lo, V^T all double-buffered in LDS (XOR swizzle); tile j+1
// staged BEFORE computing tile j so staging latency hides under compute.
// 1-D grid of 512 blocks; qt paired (15-p, p) for per-CU work balance.
__launch_bounds__(512, 2)
__global__ void k_flash(const ushort* __restrict__ Qhg, const ushort* __restrict__ Qlg,
                        const ushort* __restrict__ Khg, const ushort* __restrict__ Klg,
                        const ushort* __restrict__ vt, ushort* __restrict__ attn) {
  __shared__ char Ksh[2][16384];   // K hi [s][h] bf16, XOR swizzle ((s&7)<<4)
  __shared__ char Ksl[2][16384];   // K lo
  __shared__ char Vs[2][16384];    // V^T [h][s] bf16, XOR swizzle ((h&7)<<4)
  __shared__ char Pl[8][2176];     // per-wave P: 16 rows x 136B pitch
  const int b = blockIdx.x;
  const int vv = b >> 8, u = b & 255;
  const int hid = u >> 3, p = u & 7;
  const int qt = vv ? p : (15 - p);           // paired workload balance
  const int bq = hid >> 4, n = hid & 15, g = n >> 2;
  const int tid = threadIdx.x, w = tid >> 6, l = tid & 63;
  const int lr = l & 15, lk = l >> 4;
  const int t0 = qt * 128;
  const int qrow = t0 + w * 16;

  bf16x8 qfh[4], qfl[4];
  {
    const size_t qb = ((size_t)(bq * Tt + qrow + lr)) * 2048 + n * HD + lk * 8;
#pragma unroll
    for (int kt = 0; kt < 4; ++kt) {
      qfh[kt] = *(const bf16x8*)(Qhg + qb + kt * 32);
      qfl[kt] = *(const bf16x8*)(Qlg + qb + kt * 32);
    }
  }
  f32x4 O[8];
#pragma unroll
  for (int hb = 0; hb < 8; ++hb) O[hb] = (f32x4){0.f, 0.f, 0.f, 0.f};
  float mrow[4] = {-INFINITY, -INFINITY, -INFINITY, -INFINITY};
  float lrow[4] = {0.f, 0.f, 0.f, 0.f};

  const size_t kgbase = (size_t)(bq * Tt) * VC + g * HD;
  const size_t vgbase = (size_t)(bq * 4 + g) * HD * Tt;
  const int ntiles = 2 * qt + 2;

  // precomputed staging addresses (chunk c = cc*512+tid)
  int srow[2], koin[2], hrow[2], voin[2];
#pragma unroll
  for (int cc = 0; cc < 2; ++cc) {
    int c = cc * 512 + tid;
    srow[cc] = c >> 4;
    koin[cc] = (((c & 15) << 4) ^ ((srow[cc] & 7) << 4)) >> 1;
    hrow[cc] = c >> 3;
    voin[cc] = (((c & 7) << 4) ^ ((hrow[cc] & 7) << 4)) >> 1;
  }

#define STAGE(buf, s0s)                                                          \
  {                                                                              \
    _Pragma("unroll")                                                            \
    for (int cc = 0; cc < 2; ++cc) {                                             \
      int c16 = (cc * 512 + tid) * 16;                                           \
      size_t ksrc = kgbase + (size_t)((s0s) + srow[cc]) * VC + koin[cc];         \
      gload16(Ksh[buf] + c16, Khg + ksrc);                                       \
      gload16(Ksl[buf] + c16, Klg + ksrc);                                       \
      gload16(Vs[buf] + c16, vt + vgbase + (size_t)hrow[cc] * Tt + (s0s) + voin[cc]); \
    }                                                                            \
  }

  STAGE(0, 0);
  __syncthreads();

  for (int j = 0; j < ntiles; ++j) {
    const int cur = j & 1;
    if (j + 1 < ntiles) STAGE(cur ^ 1, (j + 1) * 64);
    const int s0 = j * 64;
    if (s0 <= qrow + 15) {
      f32x4 sc[4];
#pragma unroll
      for (int ns = 0; ns < 4; ++ns) {
        f32x4 a = (f32x4){0.f, 0.f, 0.f, 0.f};
        int sl = ns * 16 + lr;
#pragma unroll
        for (int kt = 0; kt < 4; ++kt) {
          int inner = (kt * 64 + lk * 16) ^ ((sl & 7) << 4);
          bf16x8 kfh = *(const bf16x8*)(Ksh[cur] + sl * 256 + inner);
          bf16x8 kfl = *(const bf16x8*)(Ksl[cur] + sl * 256 + inner);
          a = __builtin_amdgcn_mfma_f32_16x16x32_bf16(qfh[kt], kfh, a, 0, 0, 0);
          a = __builtin_amdgcn_mfma_f32_16x16x32_bf16(qfl[kt], kfh, a, 0, 0, 0);
          a = __builtin_amdgcn_mfma_f32_16x16x32_bf16(qfh[kt], kfl, a, 0, 0, 0);
        }
        sc[ns] = a;
      }
      if (s0 + 63 > qrow) {         // diagonal tile for this wave: mask s > t
#pragma unroll
        for (int ns = 0; ns < 4; ++ns) {
          int scol = s0 + ns * 16 + lr;
#pragma unroll
          for (int r = 0; r < 4; ++r)
            if (scol > qrow + lk * 4 + r) sc[ns][r] = -INFINITY;
        }
      }
      float scl[4], rs[4];
#pragma unroll
      for (int r = 0; r < 4; ++r) {
        float v0 = fmaxf(fmaxf(sc[0][r], sc[1][r]), fmaxf(sc[2][r], sc[3][r]));
#pragma unroll
        for (int d = 1; d < 16; d <<= 1) v0 = fmaxf(v0, __shfl_xor(v0, d));
        float mn = fmaxf(mrow[r], v0);
        scl[r] = __expf(mrow[r] - mn);
        mrow[r] = mn;
        rs[r] = 0.f;
      }
#pragma unroll
      for (int ns = 0; ns < 4; ++ns)
#pragma unroll
        for (int r = 0; r < 4; ++r) {
          float pv = __expf(sc[ns][r] - mrow[r]);
          rs[r] += pv;
          *(ushort*)(Pl[w] + (lk * 4 + r) * 136 + (ns * 16 + lr) * 2) = f2b(pv);
        }
#pragma unroll
      for (int r = 0; r < 4; ++r) {
#pragma unroll
        for (int d = 1; d < 16; d <<= 1) rs[r] += __shfl_xor(rs[r], d);
        lrow[r] = lrow[r] * scl[r] + rs[r];
      }
#pragma unroll
      for (int hb = 0; hb < 8; ++hb)
#pragma unroll
        for (int r = 0; r < 4; ++r) O[hb][r] *= scl[r];
      // PV: P[16][64] x V[64][128]; A-frag from Pl via 2x b64 (pitch 136)
      union U8 { uint2 u[2]; bf16x8 v; };
      U8 pa0, pa1;
      const char* pb = Pl[w] + lr * 136 + lk * 16;
      pa0.u[0] = *(const uint2*)(pb);
      pa0.u[1] = *(const uint2*)(pb + 8);
      pa1.u[0] = *(const uint2*)(pb + 64);
      pa1.u[1] = *(const uint2*)(pb + 72);
#pragma unroll
      for (int hb = 0; hb < 8; ++hb) {
        int h = hb * 16 + lr;
        int inner0 = (lk * 16) ^ ((h & 7) << 4);
        bf16x8 vf0 = *(const bf16x8*)(Vs[cur] + h * 128 + inner0);
        O[hb] = __builtin_amdgcn_mfma_f32_16x16x32_bf16(pa0.v, vf0, O[hb], 0, 0, 0);
        int inner1 = (64 + lk * 16) ^ ((h & 7) << 4);
        bf16x8 vf1 = *(const bf16x8*)(Vs[cur] + h * 128 + inner1);
        O[hb] = __builtin_amdgcn_mfma_f32_16x16x32_bf16(pa1.v, vf1, O[hb], 0, 0, 0);
      }
    }
    __syncthreads();
  }
#undef STAGE
  float inv[4];
#pragma unroll
  for (int r = 0; r < 4; ++r) inv[r] = 1.f / lrow[r];
#pragma unroll
  for (int hb = 0; hb < 8; ++hb)
#pragma unroll
    for (int r = 0; r < 4; ++r) {
      size_t orow = (size_t)(bq * Tt + qrow + lk * 4 + r);
      attn[orow * 2048 + n * HD + hb * 16 + lr] = f2b(O[hb][r] * inv[r]);
    }
}

// ---------------- launch ----------------
extern "C" void kernel_launch(void* const* d_in, const int* in_sizes, int n_in,
                              void* d_out, int out_size, void* d_ws, size_t ws_size,
                              hipStream_t stream) {
  const float* X  = (const float*)d_in[0];
  const int*   qp = (const int*)d_in[1];
  const float* Wq = (const float*)d_in[2];
  const float* Wk = (const float*)d_in[3];
  const float* Wv = (const float*)d_in[4];
  const float* Wo = (const float*)d_in[5];
  float* out = (float*)d_out;
  char* ws = (char*)d_ws;

  ushort* Xh     = (ushort*)(ws + 0);            // 16.78 MB  (-> Qh after GEMM)
  ushort* Xl     = (ushort*)(ws + 16777216);     // 16.78 MB  (-> Ql)
  ushort* WqkvTh = (ushort*)(ws + 33554432);     // 12.58 MB  (-> Kh,Kl,VT)
  ushort* WqkvTl = (ushort*)(ws + 46137344);     // 12.58 MB
  ushort* WoT    = (ushort*)(ws + 58720256);     //  8.39 MB
  float*  QKf    = (float*) (ws + 67108864);     // 41.94 MB  (-> attn)
  ushort* Vb     = (ushort*)(ws + 109051904);    //  4.19 MB
  float*  tab    = (float*) (ws + 113246208);    //  2.10 MB  (end ~115.3 MB)

  ushort* Qh   = Xh;
  ushort* Ql   = Xl;
  ushort* Kh   = (ushort*)(ws + 33554432);
  ushort* Kl   = (ushort*)(ws + 37748736);
  ushort* VT   = (ushort*)(ws + 41943040);
  ushort* attn = (ushort*)(ws + 67108864);

  dim3 tb(32, 8);
  k_split_x<<<(Mrows * Dd / 4 + 255) / 256, 256, 0, stream>>>(X, Xh, Xl, Mrows * Dd / 4);
  k_tconv_split<<<dim3(64, 64), tb, 0, stream>>>(Wq, WqkvTh, WqkvTl, Dd, 2048);
  k_tconv_split<<<dim3(16, 64), tb, 0, stream>>>(Wk, WqkvTh + (size_t)KOFF * Dd,
                                                 WqkvTl + (size_t)KOFF * Dd, Dd, 512);
  k_tconv_split<<<dim3(16, 64), tb, 0, stream>>>(Wv, WqkvTh + (size_t)VOFF * Dd,
                                                 WqkvTl + (size_t)VOFF * Dd, Dd, 512);
  k_tconv<<<dim3(64, 64), tb, 0, stream>>>(Wo, WoT, 2048, 2048);
  k_gemm_qkv<<<dim3(24, 32), 256, 0, stream>>>(Xh, Xl, WqkvTh, WqkvTl, QKf, Vb);
  k_rope_tab<<<(Mrows * 64 + 255) / 256, 256, 0, stream>>>(qp, tab);
  k_rope<<<(Mrows * 160 + 255) / 256, 256, 0, stream>>>(QKf, tab, Qh, Ql, Kh, Kl);
  k_vt<<<dim3(Tt / 32, HD / 32, Bb * NK), tb, 0, stream>>>(Vb, VT);
  k_flash<<<dim3(512), 512, 0, stream>>>(Qh, Ql, Kh, Kl, VT, attn);
  k_gemm_bt<<<dim3(Dd / 128, Mrows / 128), 256, 0, stream>>>(attn, WoT, out, Mrows, Dd, Dd);
}

// Round 5
// 251.027 us; speedup vs baseline: 1.8279x; 1.4305x over previous
//
#include <hip/hip_runtime.h>
#include <math.h>

#define DEVI static __device__ __forceinline__

using f16x8 = __attribute__((ext_vector_type(8))) _Float16;
using f32x4  = __attribute__((ext_vector_type(4))) float;

constexpr int Bb = 2, Tt = 2048, Dd = 2048, NQ = 16, NK = 4, HD = 128;
constexpr int Mrows = Bb * Tt;               // 4096
constexpr int QKVC  = NQ*HD + 2*NK*HD;       // 3072
constexpr int KOFF  = NQ*HD;                 // 2048
constexpr int VOFF  = NQ*HD + NK*HD;         // 2560

DEVI ushort f2h(float f) {                   // fp32 -> fp16 (RNE via v_cvt)
  _Float16 h = (_Float16)f;
  union { _Float16 h; ushort u; } v; v.h = h;
  return v.u;
}
DEVI float h2f(ushort u) {
  union { ushort u; _Float16 h; } v; v.u = u;
  return (float)v.h;
}

typedef const __attribute__((address_space(1))) unsigned* gp1;
typedef __attribute__((address_space(3))) unsigned* lp3;
DEVI void gload16(void* lds, const void* g) {
  __builtin_amdgcn_global_load_lds((gp1)g, (lp3)lds, 16, 0, 0);
}

// ---------------- fp32 -> fp16 convert (vectorized) ----------------
__global__ void k_cvt(const float* __restrict__ x, ushort* __restrict__ o, int n4) {
  int i = blockIdx.x * blockDim.x + threadIdx.x;
  if (i >= n4) return;
  float4 v = ((const float4*)x)[i];
  ushort4 u;
  u.x = f2h(v.x); u.y = f2h(v.y); u.z = f2h(v.z); u.w = f2h(v.w);
  ((ushort4*)o)[i] = u;
}

// ------- transpose + convert: in fp32 [R][C] -> out fp16 [C][R] -------
__global__ void k_tconv(const float* __restrict__ in, ushort* __restrict__ out, int R, int C) {
  __shared__ float t[32][33];
  const int c0 = blockIdx.x * 32, r0 = blockIdx.y * 32;
  const int tx = threadIdx.x, ty = threadIdx.y;
#pragma unroll
  for (int i = 0; i < 32; i += 8)
    t[ty + i][tx] = in[(size_t)(r0 + ty + i) * C + (c0 + tx)];
  __syncthreads();
#pragma unroll
  for (int i = 0; i < 32; i += 8)
    out[(size_t)(c0 + ty + i) * R + (r0 + tx)] = f2h(t[tx][ty + i]);
}

// ---------------- m97-style 128x128 fp16 GEMM, C = A * Bt^T ----------------
// A: [M][Kd] fp16 row-major, Bt: [N][Kd] fp16 row-major
DEVI void stv(float* p, float v)  { *p = v; }
DEVI void stv(ushort* p, float v) { *p = f2h(v); }

template <typename OT>
__launch_bounds__(256)
__global__ void k_gemm_bt(const ushort* __restrict__ A, const ushort* __restrict__ Bt,
                          OT* __restrict__ C, int M, int N, int Kd) {
  __shared__ char As[8192];   // 128 rows x 64B (32 fp16), k-slot XOR swizzled
  __shared__ char Bs[8192];
  const int tid = threadIdx.x;
  const int l = tid & 63, w = tid >> 6;
  const int wr = w >> 1, wc = w & 1;
  const int lr = l & 15, lk = l >> 4;
  const size_t row0 = (size_t)blockIdx.y * 128, col0 = (size_t)blockIdx.x * 128;

  f32x4 acc[4][4];
#pragma unroll
  for (int i = 0; i < 4; ++i)
#pragma unroll
    for (int j = 0; j < 4; ++j) acc[i][j] = (f32x4){0.f, 0.f, 0.f, 0.f};

  const int c0i = tid, c1i = tid + 256;
  const int ra0 = c0i >> 2, sa0 = (c0i & 3) ^ ((ra0 >> 1) & 3);
  const int ra1 = c1i >> 2, sa1 = (c1i & 3) ^ ((ra1 >> 1) & 3);

  for (int kt = 0; kt < Kd; kt += 32) {
    if (kt) __syncthreads();
    gload16(As + c0i * 16, A + (row0 + ra0) * Kd + kt + sa0 * 8);
    gload16(As + c1i * 16, A + (row0 + ra1) * Kd + kt + sa1 * 8);
    gload16(Bs + c0i * 16, Bt + (col0 + ra0) * Kd + kt + sa0 * 8);
    gload16(Bs + c1i * 16, Bt + (col0 + ra1) * Kd + kt + sa1 * 8);
    __syncthreads();
    f16x8 af[4], bfr[4];
#pragma unroll
    for (int i = 0; i < 4; ++i) {
      int ra = wr * 64 + i * 16 + lr;
      af[i] = *(const f16x8*)(As + ra * 64 + ((lk ^ ((ra >> 1) & 3)) << 4));
      int rb = wc * 64 + i * 16 + lr;
      bfr[i] = *(const f16x8*)(Bs + rb * 64 + ((lk ^ ((rb >> 1) & 3)) << 4));
    }
#pragma unroll
    for (int i = 0; i < 4; ++i)
#pragma unroll
      for (int j = 0; j < 4; ++j)
        acc[i][j] = __builtin_amdgcn_mfma_f32_16x16x32_f16(af[i], bfr[j], acc[i][j], 0, 0, 0);
  }
  // epilogue: D col = lane&15, row = (lane>>4)*4 + reg
#pragma unroll
  for (int i = 0; i < 4; ++i) {
    size_t r = row0 + wr * 64 + i * 16 + lk * 4;
#pragma unroll
    for (int j = 0; j < 4; ++j) {
      size_t cc = col0 + wc * 64 + j * 16 + lr;
#pragma unroll
      for (int rg = 0; rg < 4; ++rg) stv(&C[(r + rg) * N + cc], acc[i][j][rg]);
    }
  }
}

// ---------------- RoPE table (double-precision trig) ----------------
__global__ void k_rope_tab(const int* __restrict__ pos, float* __restrict__ tab) {
  int idx = blockIdx.x * blockDim.x + threadIdx.x;
  if (idx >= Mrows * 64) return;
  int m = idx >> 6, i = idx & 63;
  double a = (double)pos[m] * exp2(-0.20762050593045952 * (double)i);
  tab[idx * 2]     = (float)cos(a);
  tab[idx * 2 + 1] = (float)sin(a);
}

// ---------------- RoPE apply in-place on q,k columns of fp16 QKV ----------------
__global__ void k_rope(ushort* __restrict__ qkv, const float* __restrict__ tab) {
  int idx = blockIdx.x * blockDim.x + threadIdx.x;
  if (idx >= Mrows * 20 * 8) return;
  int chunk = idx & 7;          // 8 pairs each
  int h20 = (idx >> 3) % 20;    // 16 q heads + 4 k heads
  int m = idx / 160;
  int colbase = (h20 < 16) ? h20 * 128 : (KOFF + (h20 - 16) * 128);
  size_t base = (size_t)m * QKVC + colbase + chunk * 8;
  union { uint4 v; ushort s[8]; } A1, A2, O1, O2;
  A1.v = *(const uint4*)(qkv + base);
  A2.v = *(const uint4*)(qkv + base + 64);
  const float* tp = tab + ((size_t)m * 64 + chunk * 8) * 2;
#pragma unroll
  for (int j = 0; j < 8; ++j) {
    float c = tp[2 * j], s = tp[2 * j + 1];
    float x1 = h2f(A1.s[j]), x2 = h2f(A2.s[j]);
    O1.s[j] = f2h(x1 * c - x2 * s);
    O2.s[j] = f2h(x2 * c + x1 * s);
  }
  *(uint4*)(qkv + base) = O1.v;
  *(uint4*)(qkv + base + 64) = O2.v;
}

// ------- V transpose: QKV v-cols -> VT[(b*4+g)*128 + h][s] -------
__global__ void k_vt(const ushort* __restrict__ qkv, ushort* __restrict__ vt) {
  __shared__ ushort t[32][33];
  const int bg = blockIdx.z, bq = bg >> 2, g = bg & 3;
  const int s0 = blockIdx.x * 32, h0 = blockIdx.y * 32;
  const int tx = threadIdx.x, ty = threadIdx.y;
#pragma unroll
  for (int i = 0; i < 32; i += 8)
    t[ty + i][tx] = qkv[(size_t)(bq * Tt + s0 + ty + i) * QKVC + VOFF + g * HD + h0 + tx];
  __syncthreads();
#pragma unroll
  for (int i = 0; i < 32; i += 8)
    vt[((size_t)bg * HD + h0 + ty + i) * Tt + (s0 + tx)] = t[tx][ty + i];
}

// ---------------- causal GQA flash attention v4: fp16, 2-phase dbuf ----------------
// 512 threads / 8 waves; QB=128 (wave w: 16 rows); KVBLK=64. K, V^T double-
// buffered in LDS (XOR swizzle), single-term fp16 QK^T. P relay via XOR-
// swizzled 128B-pitch LDS (16 KB). LDS total = 80 KB -> 2 blocks/CU.
// 1-D grid of 512 blocks; qt paired (15-p, p) for per-CU work balance.
__launch_bounds__(512, 4)
__global__ void k_flash(const ushort* __restrict__ qkv, const ushort* __restrict__ vt,
                        ushort* __restrict__ attn) {
  __shared__ char Ks[2][16384];   // K [s][h] fp16, XOR swizzle ((s&7)<<4)
  __shared__ char Vs[2][16384];   // V^T [h][s] fp16, XOR swizzle ((h&7)<<4)
  __shared__ char Pl[8][2048];    // per-wave P: 16 rows x 128B, slot^=(row&7)
  const int b = blockIdx.x;
  const int vv = b >> 8, u = b & 255;
  const int hid = u >> 3, p = u & 7;
  const int qt = vv ? p : (15 - p);           // paired workload balance
  const int bq = hid >> 4, n = hid & 15, g = n >> 2;
  const int tid = threadIdx.x, w = tid >> 6, l = tid & 63;
  const int lr = l & 15, lk = l >> 4;
  const int t0 = qt * 128;
  const int qrow = t0 + w * 16;

  f16x8 qf[4];
  {
    const size_t qb = ((size_t)(bq * Tt + qrow + lr)) * QKVC + n * HD + lk * 8;
#pragma unroll
    for (int kt = 0; kt < 4; ++kt) qf[kt] = *(const f16x8*)(qkv + qb + kt * 32);
  }
  f32x4 O[8];
#pragma unroll
  for (int hb = 0; hb < 8; ++hb) O[hb] = (f32x4){0.f, 0.f, 0.f, 0.f};
  float mrow[4] = {-INFINITY, -INFINITY, -INFINITY, -INFINITY};
  float lrow[4] = {0.f, 0.f, 0.f, 0.f};

  const size_t kgbase = (size_t)(bq * Tt) * QKVC + KOFF + g * HD;
  const size_t vgbase = (size_t)(bq * 4 + g) * HD * Tt;
  const int ntiles = 2 * qt + 2;

  // precomputed staging addresses (chunk c = cc*512+tid)
  int srow[2], koin[2], hrow[2], voin[2];
#pragma unroll
  for (int cc = 0; cc < 2; ++cc) {
    int c = cc * 512 + tid;
    srow[cc] = c >> 4;
    koin[cc] = (((c & 15) << 4) ^ ((srow[cc] & 7) << 4)) >> 1;
    hrow[cc] = c >> 3;
    voin[cc] = (((c & 7) << 4) ^ ((hrow[cc] & 7) << 4)) >> 1;
  }

#define STAGE(buf, s0s)                                                              \
  {                                                                                  \
    _Pragma("unroll")                                                                \
    for (int cc = 0; cc < 2; ++cc) {                                                 \
      int c16 = (cc * 512 + tid) * 16;                                               \
      gload16(Ks[buf] + c16, qkv + kgbase + (size_t)((s0s) + srow[cc]) * QKVC + koin[cc]); \
      gload16(Vs[buf] + c16, vt + vgbase + (size_t)hrow[cc] * Tt + (s0s) + voin[cc]); \
    }                                                                                \
  }

  STAGE(0, 0);
  __syncthreads();

  for (int j = 0; j < ntiles; ++j) {
    const int cur = j & 1;
    if (j + 1 < ntiles) STAGE(cur ^ 1, (j + 1) * 64);
    const int s0 = j * 64;
    if (s0 <= qrow + 15) {
      f32x4 sc[4];
#pragma unroll
      for (int ns = 0; ns < 4; ++ns) {
        f32x4 a = (f32x4){0.f, 0.f, 0.f, 0.f};
        int sl = ns * 16 + lr;
#pragma unroll
        for (int kt = 0; kt < 4; ++kt) {
          int inner = (kt * 64 + lk * 16) ^ ((sl & 7) << 4);
          f16x8 kf = *(const f16x8*)(Ks[cur] + sl * 256 + inner);
          a = __builtin_amdgcn_mfma_f32_16x16x32_f16(qf[kt], kf, a, 0, 0, 0);
        }
        sc[ns] = a;
      }
      if (s0 + 63 > qrow) {         // diagonal tile for this wave: mask s > t
#pragma unroll
        for (int ns = 0; ns < 4; ++ns) {
          int scol = s0 + ns * 16 + lr;
#pragma unroll
          for (int r = 0; r < 4; ++r)
            if (scol > qrow + lk * 4 + r) sc[ns][r] = -INFINITY;
        }
      }
      float scl[4], rs[4];
#pragma unroll
      for (int r = 0; r < 4; ++r) {
        float v0 = fmaxf(fmaxf(sc[0][r], sc[1][r]), fmaxf(sc[2][r], sc[3][r]));
#pragma unroll
        for (int d = 1; d < 16; d <<= 1) v0 = fmaxf(v0, __shfl_xor(v0, d));
        float mn = fmaxf(mrow[r], v0);
        scl[r] = __expf(mrow[r] - mn);
        mrow[r] = mn;
        rs[r] = 0.f;
      }
#pragma unroll
      for (int ns = 0; ns < 4; ++ns)
#pragma unroll
        for (int r = 0; r < 4; ++r) {
          float pv = __expf(sc[ns][r] - mrow[r]);
          rs[r] += pv;
          int q = lk * 4 + r;
          *(ushort*)(Pl[w] + q * 128 + ((ns * 32 + lr * 2) ^ ((q & 7) << 4))) = f2h(pv);
        }
#pragma unroll
      for (int r = 0; r < 4; ++r) {
#pragma unroll
        for (int d = 1; d < 16; d <<= 1) rs[r] += __shfl_xor(rs[r], d);
        lrow[r] = lrow[r] * scl[r] + rs[r];
      }
#pragma unroll
      for (int hb = 0; hb < 8; ++hb)
#pragma unroll
        for (int r = 0; r < 4; ++r) O[hb][r] *= scl[r];
      // PV: P[16][64] x V[64][128]; A-frag row lr, slot (kt2*4+lk)^(lr&7)
      const char* pb = Pl[w] + lr * 128;
      const int sw = (lr & 7) << 4;
      f16x8 pa0 = *(const f16x8*)(pb + ((lk * 16) ^ sw));
      f16x8 pa1 = *(const f16x8*)(pb + ((64 + lk * 16) ^ sw));
#pragma unroll
      for (int hb = 0; hb < 8; ++hb) {
        int h = hb * 16 + lr;
        int inner0 = (lk * 16) ^ ((h & 7) << 4);
        f16x8 vf0 = *(const f16x8*)(Vs[cur] + h * 128 + inner0);
        O[hb] = __builtin_amdgcn_mfma_f32_16x16x32_f16(pa0, vf0, O[hb], 0, 0, 0);
        int inner1 = (64 + lk * 16) ^ ((h & 7) << 4);
        f16x8 vf1 = *(const f16x8*)(Vs[cur] + h * 128 + inner1);
        O[hb] = __builtin_amdgcn_mfma_f32_16x16x32_f16(pa1, vf1, O[hb], 0, 0, 0);
      }
    }
    __syncthreads();
  }
#undef STAGE
  float inv[4];
#pragma unroll
  for (int r = 0; r < 4; ++r) inv[r] = 1.f / lrow[r];
#pragma unroll
  for (int hb = 0; hb < 8; ++hb)
#pragma unroll
    for (int r = 0; r < 4; ++r) {
      size_t orow = (size_t)(bq * Tt + qrow + lk * 4 + r);
      attn[orow * 2048 + n * HD + hb * 16 + lr] = f2h(O[hb][r] * inv[r]);
    }
}

// ---------------- launch ----------------
extern "C" void kernel_launch(void* const* d_in, const int* in_sizes, int n_in,
                              void* d_out, int out_size, void* d_ws, size_t ws_size,
                              hipStream_t stream) {
  const float* X  = (const float*)d_in[0];
  const int*   qp = (const int*)d_in[1];
  const float* Wq = (const float*)d_in[2];
  const float* Wk = (const float*)d_in[3];
  const float* Wv = (const float*)d_in[4];
  const float* Wo = (const float*)d_in[5];
  float* out = (float*)d_out;
  char* ws = (char*)d_ws;

  ushort* Xf    = (ushort*)(ws + 0);          // 4096x2048 fp16      (16.78 MB)
  ushort* WqkvT = (ushort*)(ws + 16777216);   // 3072x2048 fp16      (12.58 MB)
  ushort* WoT   = (ushort*)(ws + 29360128);   // 2048x2048 fp16      ( 8.39 MB)
  ushort* QKV   = (ushort*)(ws + 37748736);   // 4096x3072 fp16      (25.17 MB)
  ushort* VT    = (ushort*)(ws + 62914560);   // 8x128x2048 fp16     ( 4.19 MB)
  ushort* attn  = (ushort*)(ws + 67108864);   // 4096x2048 fp16      (16.78 MB)
  float*  tab   = (float*)(ws + 83886080);    // 4096x64x2 f32       ( 2.10 MB)

  dim3 tb(32, 8);
  // 1. X -> fp16
  k_cvt<<<(Mrows * Dd / 4 + 255) / 256, 256, 0, stream>>>(X, Xf, Mrows * Dd / 4);
  // 2. weights -> fp16, transposed to [n][k] (B^T layout); Wq/Wk/Wv fused rows
  k_tconv<<<dim3(64, 64), tb, 0, stream>>>(Wq, WqkvT, Dd, NQ * HD);
  k_tconv<<<dim3(16, 64), tb, 0, stream>>>(Wk, WqkvT + (size_t)KOFF * Dd, Dd, NK * HD);
  k_tconv<<<dim3(16, 64), tb, 0, stream>>>(Wv, WqkvT + (size_t)VOFF * Dd, Dd, NK * HD);
  k_tconv<<<dim3(64, 64), tb, 0, stream>>>(Wo, WoT, NQ * HD, Dd);
  // 3. fused QKV projection (fp16 in, fp16 out)
  k_gemm_bt<ushort><<<dim3(QKVC / 128, Mrows / 128), 256, 0, stream>>>(
      Xf, WqkvT, QKV, Mrows, QKVC, Dd);
  // 4+5. RoPE (fp32 math, in-place on fp16 q,k)
  k_rope_tab<<<(Mrows * 64 + 255) / 256, 256, 0, stream>>>(qp, tab);
  k_rope<<<(Mrows * 160 + 255) / 256, 256, 0, stream>>>(QKV, tab);
  // 6. V transpose for PV B-operand
  k_vt<<<dim3(Tt / 32, HD / 32, Bb * NK), tb, 0, stream>>>(QKV, VT);
  // 7. flash attention
  k_flash<<<dim3(512), 512, 0, stream>>>(QKV, VT, attn);
  // 8. output projection
  k_gemm_bt<float><<<dim3(Dd / 128, Mrows / 128), 256, 0, stream>>>(
      attn, WoT, out, Mrows, Dd, Dd);
}

// Round 7
// 216.793 us; speedup vs baseline: 2.1166x; 1.1579x over previous
//
#include <hip/hip_runtime.h>
#include <math.h>

#define DEVI static __device__ __forceinline__

using f16x8 = __attribute__((ext_vector_type(8))) _Float16;
using h16x2 = __attribute__((ext_vector_type(2))) __fp16;   // cvt_pkrtz native type
using f32x4  = __attribute__((ext_vector_type(4))) float;

constexpr int Bb = 2, Tt = 2048, Dd = 2048, NQ = 16, NK = 4, HD = 128;
constexpr int Mrows = Bb * Tt;               // 4096
constexpr int QKVC  = NQ*HD + 2*NK*HD;       // 3072
constexpr int KOFF  = NQ*HD;                 // 2048
constexpr int VOFF  = NQ*HD + NK*HD;         // 2560

DEVI ushort f2h(float f) {                   // fp32 -> fp16 (RNE via v_cvt)
  _Float16 h = (_Float16)f;
  union { _Float16 h; ushort u; } v; v.h = h;
  return v.u;
}
DEVI float h2f(ushort u) {
  union { ushort u; _Float16 h; } v; v.u = u;
  return (float)v.h;
}

typedef const __attribute__((address_space(1))) unsigned* gp1;
typedef __attribute__((address_space(3))) unsigned* lp3;
DEVI void gload16(void* lds, const void* g) {
  __builtin_amdgcn_global_load_lds((gp1)g, (lp3)lds, 16, 0, 0);
}

// ---------------- fp32 -> fp16 convert (vectorized) ----------------
__global__ void k_cvt(const float* __restrict__ x, ushort* __restrict__ o, int n4) {
  int i = blockIdx.x * blockDim.x + threadIdx.x;
  if (i >= n4) return;
  float4 v = ((const float4*)x)[i];
  ushort4 u;
  u.x = f2h(v.x); u.y = f2h(v.y); u.z = f2h(v.z); u.w = f2h(v.w);
  ((ushort4*)o)[i] = u;
}

// ------- transpose + convert: in fp32 [R][C] -> out fp16 [C][R] -------
__global__ void k_tconv(const float* __restrict__ in, ushort* __restrict__ out, int R, int C) {
  __shared__ float t[32][33];
  const int c0 = blockIdx.x * 32, r0 = blockIdx.y * 32;
  const int tx = threadIdx.x, ty = threadIdx.y;
#pragma unroll
  for (int i = 0; i < 32; i += 8)
    t[ty + i][tx] = in[(size_t)(r0 + ty + i) * C + (c0 + tx)];
  __syncthreads();
#pragma unroll
  for (int i = 0; i < 32; i += 8)
    out[(size_t)(c0 + ty + i) * R + (r0 + tx)] = f2h(t[tx][ty + i]);
}

// ---------------- m97-style 128x128 fp16 GEMM, C = A * Bt^T ----------------
DEVI void stv(float* p, float v)  { *p = v; }
DEVI void stv(ushort* p, float v) { *p = f2h(v); }

template <typename OT>
__launch_bounds__(256)
__global__ void k_gemm_bt(const ushort* __restrict__ A, const ushort* __restrict__ Bt,
                          OT* __restrict__ C, int M, int N, int Kd) {
  __shared__ char As[8192];   // 128 rows x 64B (32 fp16), k-slot XOR swizzled
  __shared__ char Bs[8192];
  const int tid = threadIdx.x;
  const int l = tid & 63, w = tid >> 6;
  const int wr = w >> 1, wc = w & 1;
  const int lr = l & 15, lk = l >> 4;
  const size_t row0 = (size_t)blockIdx.y * 128, col0 = (size_t)blockIdx.x * 128;

  f32x4 acc[4][4];
#pragma unroll
  for (int i = 0; i < 4; ++i)
#pragma unroll
    for (int j = 0; j < 4; ++j) acc[i][j] = (f32x4){0.f, 0.f, 0.f, 0.f};

  const int c0i = tid, c1i = tid + 256;
  const int ra0 = c0i >> 2, sa0 = (c0i & 3) ^ ((ra0 >> 1) & 3);
  const int ra1 = c1i >> 2, sa1 = (c1i & 3) ^ ((ra1 >> 1) & 3);

  for (int kt = 0; kt < Kd; kt += 32) {
    if (kt) __syncthreads();
    gload16(As + c0i * 16, A + (row0 + ra0) * Kd + kt + sa0 * 8);
    gload16(As + c1i * 16, A + (row0 + ra1) * Kd + kt + sa1 * 8);
    gload16(Bs + c0i * 16, Bt + (col0 + ra0) * Kd + kt + sa0 * 8);
    gload16(Bs + c1i * 16, Bt + (col0 + ra1) * Kd + kt + sa1 * 8);
    __syncthreads();
    f16x8 af[4], bfr[4];
#pragma unroll
    for (int i = 0; i < 4; ++i) {
      int ra = wr * 64 + i * 16 + lr;
      af[i] = *(const f16x8*)(As + ra * 64 + ((lk ^ ((ra >> 1) & 3)) << 4));
      int rb = wc * 64 + i * 16 + lr;
      bfr[i] = *(const f16x8*)(Bs + rb * 64 + ((lk ^ ((rb >> 1) & 3)) << 4));
    }
#pragma unroll
    for (int i = 0; i < 4; ++i)
#pragma unroll
      for (int j = 0; j < 4; ++j)
        acc[i][j] = __builtin_amdgcn_mfma_f32_16x16x32_f16(af[i], bfr[j], acc[i][j], 0, 0, 0);
  }
#pragma unroll
  for (int i = 0; i < 4; ++i) {
    size_t r = row0 + wr * 64 + i * 16 + lk * 4;
#pragma unroll
    for (int j = 0; j < 4; ++j) {
      size_t cc = col0 + wc * 64 + j * 16 + lr;
#pragma unroll
      for (int rg = 0; rg < 4; ++rg) stv(&C[(r + rg) * N + cc], acc[i][j][rg]);
    }
  }
}

// ---------------- RoPE table (double-precision trig) ----------------
__global__ void k_rope_tab(const int* __restrict__ pos, float* __restrict__ tab) {
  int idx = blockIdx.x * blockDim.x + threadIdx.x;
  if (idx >= Mrows * 64) return;
  int m = idx >> 6, i = idx & 63;
  double a = (double)pos[m] * exp2(-0.20762050593045952 * (double)i);
  tab[idx * 2]     = (float)cos(a);
  tab[idx * 2 + 1] = (float)sin(a);
}

// ---------------- RoPE apply in-place on q,k columns of fp16 QKV ----------------
__global__ void k_rope(ushort* __restrict__ qkv, const float* __restrict__ tab) {
  int idx = blockIdx.x * blockDim.x + threadIdx.x;
  if (idx >= Mrows * 20 * 8) return;
  int chunk = idx & 7;          // 8 pairs each
  int h20 = (idx >> 3) % 20;    // 16 q heads + 4 k heads
  int m = idx / 160;
  int colbase = (h20 < 16) ? h20 * 128 : (KOFF + (h20 - 16) * 128);
  size_t base = (size_t)m * QKVC + colbase + chunk * 8;
  union { uint4 v; ushort s[8]; } A1, A2, O1, O2;
  A1.v = *(const uint4*)(qkv + base);
  A2.v = *(const uint4*)(qkv + base + 64);
  const float* tp = tab + ((size_t)m * 64 + chunk * 8) * 2;
#pragma unroll
  for (int j = 0; j < 8; ++j) {
    float c = tp[2 * j], s = tp[2 * j + 1];
    float x1 = h2f(A1.s[j]), x2 = h2f(A2.s[j]);
    O1.s[j] = f2h(x1 * c - x2 * s);
    O2.s[j] = f2h(x2 * c + x1 * s);
  }
  *(uint4*)(qkv + base) = O1.v;
  *(uint4*)(qkv + base + 64) = O2.v;
}

// ------- V transpose: QKV v-cols -> VT[(b*4+g)*128 + h][s] -------
__global__ void k_vt(const ushort* __restrict__ qkv, ushort* __restrict__ vt) {
  __shared__ ushort t[32][33];
  const int bg = blockIdx.z, bq = bg >> 2, g = bg & 3;
  const int s0 = blockIdx.x * 32, h0 = blockIdx.y * 32;
  const int tx = threadIdx.x, ty = threadIdx.y;
#pragma unroll
  for (int i = 0; i < 32; i += 8)
    t[ty + i][tx] = qkv[(size_t)(bq * Tt + s0 + ty + i) * QKVC + VOFF + g * HD + h0 + tx];
  __syncthreads();
#pragma unroll
  for (int i = 0; i < 32; i += 8)
    vt[((size_t)bg * HD + h0 + ty + i) * Tt + (s0 + tx)] = t[tx][ty + i];
}

// ---------------- causal GQA flash attention v5: swapped QK^T ----------------
// 512 threads / 8 waves; QB=128; KVBLK=64; K/V^T double-buffered (XOR swizzle).
// QK^T computed as mfma(K, Q) -> D[s][q], q = lane&15: softmax row-reduce is
// in-lane tree + 2 shfl_xor (d=16,32). P packed (cvt_pkrtz) -> 4 ds_write_b64
// per tile into per-wave swizzled relay; PV A-frag read back as 2 b128.
// Defer-max (THR=8) skips O-rescale on most tiles. setprio around MFMA.
__launch_bounds__(512, 2)
__global__ void k_flash(const ushort* __restrict__ qkv, const ushort* __restrict__ vt,
                        ushort* __restrict__ attn) {
  __shared__ char Ks[2][16384];   // K [s][h] fp16, XOR swizzle ((s&7)<<4)
  __shared__ char Vs[2][16384];   // V^T [h][s] fp16, XOR swizzle ((h&7)<<4)
  __shared__ char Pl[8][2048];    // per-wave P: 16 rows x 128B, byte^((row&7)<<4)
  const int b = blockIdx.x;
  const int vv = b >> 8, u = b & 255;
  const int hid = u >> 3, p = u & 7;
  const int qt = vv ? p : (15 - p);           // paired workload balance
  const int bq = hid >> 4, n = hid & 15, g = n >> 2;
  const int tid = threadIdx.x, w = tid >> 6, l = tid & 63;
  const int lr = l & 15, lk = l >> 4;
  const int t0 = qt * 128;
  const int qrow = t0 + w * 16;
  const int qglob = qrow + lr;                // this lane's q row (swapped layout)

  f16x8 qf[4];
  {
    const size_t qb = ((size_t)(bq * Tt + qrow + lr)) * QKVC + n * HD + lk * 8;
#pragma unroll
    for (int kt = 0; kt < 4; ++kt) qf[kt] = *(const f16x8*)(qkv + qb + kt * 32);
  }
  f32x4 O[8];
#pragma unroll
  for (int hb = 0; hb < 8; ++hb) O[hb] = (f32x4){0.f, 0.f, 0.f, 0.f};
  float m = -INFINITY, lsum = 0.f;            // softmax state for q = qglob

  const size_t kgbase = (size_t)(bq * Tt) * QKVC + KOFF + g * HD;
  const size_t vgbase = (size_t)(bq * 4 + g) * HD * Tt;
  const int ntiles = 2 * qt + 2;

  // precomputed staging addresses (chunk c = cc*512+tid)
  int srow[2], koin[2], hrow[2], voin[2];
#pragma unroll
  for (int cc = 0; cc < 2; ++cc) {
    int c = cc * 512 + tid;
    srow[cc] = c >> 4;
    koin[cc] = (((c & 15) << 4) ^ ((srow[cc] & 7) << 4)) >> 1;
    hrow[cc] = c >> 3;
    voin[cc] = (((c & 7) << 4) ^ ((hrow[cc] & 7) << 4)) >> 1;
  }

#define STAGE(buf, s0s)                                                              \
  {                                                                                  \
    _Pragma("unroll")                                                                \
    for (int cc = 0; cc < 2; ++cc) {                                                 \
      int c16 = (cc * 512 + tid) * 16;                                               \
      gload16(Ks[buf] + c16, qkv + kgbase + (size_t)((s0s) + srow[cc]) * QKVC + koin[cc]); \
      gload16(Vs[buf] + c16, vt + vgbase + (size_t)hrow[cc] * Tt + (s0s) + voin[cc]); \
    }                                                                                \
  }

  STAGE(0, 0);
  __syncthreads();

  for (int j = 0; j < ntiles; ++j) {
    const int cur = j & 1;
    if (j + 1 < ntiles) STAGE(cur ^ 1, (j + 1) * 64);
    const int s0 = j * 64;
    if (s0 <= qrow + 15) {
      // QK^T swapped: a = mfma(K, Q) -> sc[ns][r] = S[qglob][s0 + ns*16 + lk*4 + r]
      f32x4 sc[4];
      __builtin_amdgcn_s_setprio(1);
#pragma unroll
      for (int ns = 0; ns < 4; ++ns) {
        f32x4 a = (f32x4){0.f, 0.f, 0.f, 0.f};
        int sl = ns * 16 + lr;
#pragma unroll
        for (int kt = 0; kt < 4; ++kt) {
          int inner = (kt * 64 + lk * 16) ^ ((sl & 7) << 4);
          f16x8 kf = *(const f16x8*)(Ks[cur] + sl * 256 + inner);
          a = __builtin_amdgcn_mfma_f32_16x16x32_f16(kf, qf[kt], a, 0, 0, 0);
        }
        sc[ns] = a;
      }
      __builtin_amdgcn_s_setprio(0);
      if (s0 + 63 > qrow) {         // diagonal region: mask s > q per lane/reg
#pragma unroll
        for (int ns = 0; ns < 4; ++ns)
#pragma unroll
          for (int r = 0; r < 4; ++r)
            if (s0 + ns * 16 + lk * 4 + r > qglob) sc[ns][r] = -INFINITY;
      }
      // row max: in-lane tree + 2 cross shuffles
      float pm = -INFINITY;
#pragma unroll
      for (int ns = 0; ns < 4; ++ns)
        pm = fmaxf(pm, fmaxf(fmaxf(sc[ns][0], sc[ns][1]), fmaxf(sc[ns][2], sc[ns][3])));
      pm = fmaxf(pm, __shfl_xor(pm, 16));
      pm = fmaxf(pm, __shfl_xor(pm, 32));
      const bool doresc = !__all(pm - m <= 8.0f);   // defer-max (THR=8)
      float scl = 1.f;
      if (doresc) { float mn = fmaxf(m, pm); scl = __expf(m - mn); m = mn; }
      // exp + row sum
      float rs = 0.f;
#pragma unroll
      for (int ns = 0; ns < 4; ++ns) {
#pragma unroll
        for (int r = 0; r < 4; ++r) sc[ns][r] = __expf(sc[ns][r] - m);
        rs += (sc[ns][0] + sc[ns][1]) + (sc[ns][2] + sc[ns][3]);
      }
      rs += __shfl_xor(rs, 16);
      rs += __shfl_xor(rs, 32);
      // pack P -> per-wave LDS relay (row q=lr, byte 2*s ^ swz)
      char* pwb = Pl[w] + lr * 128;
      const int swz = (lr & 7) << 4;
#pragma unroll
      for (int ns = 0; ns < 4; ++ns) {
        union { h16x2 h[2]; uint2 u; } pk;
        pk.h[0] = __builtin_amdgcn_cvt_pkrtz(sc[ns][0], sc[ns][1]);
        pk.h[1] = __builtin_amdgcn_cvt_pkrtz(sc[ns][2], sc[ns][3]);
        *(uint2*)(pwb + ((ns * 32 + lk * 8) ^ swz)) = pk.u;
      }
      if (doresc) {
        float sr[4];
#pragma unroll
        for (int r = 0; r < 4; ++r) sr[r] = __shfl(scl, lk * 4 + r);
#pragma unroll
        for (int hb = 0; hb < 8; ++hb)
#pragma unroll
          for (int r = 0; r < 4; ++r) O[hb][r] *= sr[r];
        lsum = lsum * scl + rs;
      } else {
        lsum += rs;
      }
      // PV: A-frag = P[q=lr][s = 64*kt2 + 16*lk ..], B = V^T
      f16x8 pa0 = *(const f16x8*)(pwb + ((lk * 16) ^ swz));
      f16x8 pa1 = *(const f16x8*)(pwb + ((64 + lk * 16) ^ swz));
      __builtin_amdgcn_s_setprio(1);
#pragma unroll
      for (int hb = 0; hb < 8; ++hb) {
        int h = hb * 16 + lr;
        int inner0 = (lk * 16) ^ ((h & 7) << 4);
        f16x8 vf0 = *(const f16x8*)(Vs[cur] + h * 128 + inner0);
        O[hb] = __builtin_amdgcn_mfma_f32_16x16x32_f16(pa0, vf0, O[hb], 0, 0, 0);
        int inner1 = (64 + lk * 16) ^ ((h & 7) << 4);
        f16x8 vf1 = *(const f16x8*)(Vs[cur] + h * 128 + inner1);
        O[hb] = __builtin_amdgcn_mfma_f32_16x16x32_f16(pa1, vf1, O[hb], 0, 0, 0);
      }
      __builtin_amdgcn_s_setprio(0);
    }
    __syncthreads();
  }
#undef STAGE
  float iv[4];
#pragma unroll
  for (int r = 0; r < 4; ++r) iv[r] = 1.f / __shfl(lsum, lk * 4 + r);
#pragma unroll
  for (int hb = 0; hb < 8; ++hb)
#pragma unroll
    for (int r = 0; r < 4; ++r) {
      size_t orow = (size_t)(bq * Tt + qrow + lk * 4 + r);
      attn[orow * 2048 + n * HD + hb * 16 + lr] = f2h(O[hb][r] * iv[r]);
    }
}

// ---------------- launch ----------------
extern "C" void kernel_launch(void* const* d_in, const int* in_sizes, int n_in,
                              void* d_out, int out_size, void* d_ws, size_t ws_size,
                              hipStream_t stream) {
  const float* X  = (const float*)d_in[0];
  const int*   qp = (const int*)d_in[1];
  const float* Wq = (const float*)d_in[2];
  const float* Wk = (const float*)d_in[3];
  const float* Wv = (const float*)d_in[4];
  const float* Wo = (const float*)d_in[5];
  float* out = (float*)d_out;
  char* ws = (char*)d_ws;

  ushort* Xf    = (ushort*)(ws + 0);          // 4096x2048 fp16      (16.78 MB)
  ushort* WqkvT = (ushort*)(ws + 16777216);   // 3072x2048 fp16      (12.58 MB)
  ushort* WoT   = (ushort*)(ws + 29360128);   // 2048x2048 fp16      ( 8.39 MB)
  ushort* QKV   = (ushort*)(ws + 37748736);   // 4096x3072 fp16      (25.17 MB)
  ushort* VT    = (ushort*)(ws + 62914560);   // 8x128x2048 fp16     ( 4.19 MB)
  ushort* attn  = (ushort*)(ws + 67108864);   // 4096x2048 fp16      (16.78 MB)
  float*  tab   = (float*)(ws + 83886080);    // 4096x64x2 f32       ( 2.10 MB)

  dim3 tb(32, 8);
  // 1. X -> fp16
  k_cvt<<<(Mrows * Dd / 4 + 255) / 256, 256, 0, stream>>>(X, Xf, Mrows * Dd / 4);
  // 2. weights -> fp16, transposed to [n][k] (B^T layout); Wq/Wk/Wv fused rows
  k_tconv<<<dim3(64, 64), tb, 0, stream>>>(Wq, WqkvT, Dd, NQ * HD);
  k_tconv<<<dim3(16, 64), tb, 0, stream>>>(Wk, WqkvT + (size_t)KOFF * Dd, Dd, NK * HD);
  k_tconv<<<dim3(16, 64), tb, 0, stream>>>(Wv, WqkvT + (size_t)VOFF * Dd, Dd, NK * HD);
  k_tconv<<<dim3(64, 64), tb, 0, stream>>>(Wo, WoT, NQ * HD, Dd);
  // 3. fused QKV projection (fp16 in, fp16 out)
  k_gemm_bt<ushort><<<dim3(QKVC / 128, Mrows / 128), 256, 0, stream>>>(
      Xf, WqkvT, QKV, Mrows, QKVC, Dd);
  // 4+5. RoPE (fp32 math, in-place on fp16 q,k)
  k_rope_tab<<<(Mrows * 64 + 255) / 256, 256, 0, stream>>>(qp, tab);
  k_rope<<<(Mrows * 160 + 255) / 256, 256, 0, stream>>>(QKV, tab);
  // 6. V transpose for PV B-operand
  k_vt<<<dim3(Tt / 32, HD / 32, Bb * NK), tb, 0, stream>>>(QKV, VT);
  // 7. flash attention
  k_flash<<<dim3(512), 512, 0, stream>>>(QKV, VT, attn);
  // 8. output projection
  k_gemm_bt<float><<<dim3(Dd / 128, Mrows / 128), 256, 0, stream>>>(
      attn, WoT, out, Mrows, Dd, Dd);
}